// Round 6
// baseline (5131.655 us; speedup 1.0000x reference)
//
#include <hip/hip_runtime.h>

#define DIM 2048
#define LEAK 0.2f

typedef __bf16 bf16x8 __attribute__((ext_vector_type(8)));
typedef float  f32x4  __attribute__((ext_vector_type(4)));
typedef unsigned int u32x4 __attribute__((ext_vector_type(4)));
typedef int    i32x4  __attribute__((ext_vector_type(4)));

static __device__ __forceinline__ unsigned short f2bf(float f) {
    unsigned int x = __float_as_uint(f);
    return (unsigned short)((x + 0x7fffu + ((x >> 16) & 1u)) >> 16);  // RNE
}
static __device__ __forceinline__ float bf2f(unsigned short h) {
    return __uint_as_float(((unsigned int)h) << 16);
}

static __device__ __forceinline__ void async16(const void* g, void* s) {
    __builtin_amdgcn_global_load_lds(
        (const __attribute__((address_space(1))) void*)g,
        (__attribute__((address_space(3))) void*)s, 16, 0, 0);
}

static __device__ __forceinline__ bf16x8 ld_bf16_frag(const char* p) {
    union { u32x4 u; bf16x8 v; } cv;
    cv.u = *(const u32x4*)p;   // ds_read_b128
    return cv.v;
}

// ---------------- prep kernels ----------------

__global__ __launch_bounds__(256) void split_kernel(
    const float* __restrict__ in,
    unsigned short* __restrict__ hi, unsigned short* __restrict__ lo) {
    int idx = blockIdx.x * 256 + threadIdx.x;
    float4 v = ((const float4*)in)[idx];
    ushort4 h, l;
    h.x = f2bf(v.x); l.x = f2bf(v.x - bf2f(h.x));
    h.y = f2bf(v.y); l.y = f2bf(v.y - bf2f(h.y));
    h.z = f2bf(v.z); l.z = f2bf(v.z - bf2f(h.z));
    h.w = f2bf(v.w); l.w = f2bf(v.w - bf2f(h.w));
    ((ushort4*)hi)[idx] = h;
    ((ushort4*)lo)[idx] = l;
}

__global__ __launch_bounds__(256) void transpose_split(
    const float* __restrict__ in,
    unsigned short* __restrict__ hiT, unsigned short* __restrict__ loT) {
    __shared__ float t[32][33];
    int bx = blockIdx.x, by = blockIdx.y;
    int tx = threadIdx.x & 31, ty4 = (threadIdx.x >> 5) << 2;
#pragma unroll
    for (int i = 0; i < 4; i++)
        t[ty4 + i][tx] = in[(size_t)(by * 32 + ty4 + i) * DIM + bx * 32 + tx];
    __syncthreads();
#pragma unroll
    for (int i = 0; i < 4; i++) {
        float v = t[tx][ty4 + i];
        size_t o = (size_t)(bx * 32 + ty4 + i) * DIM + by * 32 + tx;
        unsigned short h = f2bf(v);
        hiT[o] = h;
        loT[o] = f2bf(v - bf2f(h));
    }
}

__global__ __launch_bounds__(256) void transpose_i8(
    const float* __restrict__ in, signed char* __restrict__ outT) {
    __shared__ float t[32][33];
    int bx = blockIdx.x, by = blockIdx.y;
    int tx = threadIdx.x & 31, ty4 = (threadIdx.x >> 5) << 2;
#pragma unroll
    for (int i = 0; i < 4; i++)
        t[ty4 + i][tx] = in[(size_t)(by * 32 + ty4 + i) * DIM + bx * 32 + tx];
    __syncthreads();
#pragma unroll
    for (int i = 0; i < 4; i++)
        outT[(size_t)(bx * 32 + ty4 + i) * DIM + by * 32 + tx] =
            (signed char)t[tx][ty4 + i];
}

// adjT[n][k] -> fragment-packed Bp: block (nf,kc) is 1KB, lane L holds
// col = nf*16 + (L&15), k bytes [kc*64 + (L>>4)*16, +16).
__global__ __launch_bounds__(256) void pack_b(
    const signed char* __restrict__ adjT, signed char* __restrict__ Bp) {
    int t = blockIdx.x * 256 + threadIdx.x;           // 262144 threads
    int lane = t & 63, kc = (t >> 6) & 31, nf = t >> 11;
    int col = nf * 16 + (lane & 15);
    int k0 = kc * 64 + (lane >> 4) * 16;
    i32x4 v = *(const i32x4*)(adjT + (size_t)col * DIM + k0);
    *(i32x4*)(Bp + (size_t)t * 16) = v;
}

// fp32 state -> int15 hi/lo, fragment-packed (same block layout as pack_b,
// rows instead of cols).
__global__ __launch_bounds__(256) void quant_pack(
    const float* __restrict__ st,
    signed char* __restrict__ Sh, signed char* __restrict__ Sl) {
    int t = blockIdx.x * 256 + threadIdx.x;           // 262144 threads
    int lane = t & 63, kc = (t >> 6) & 31, fm = t >> 11;
    int row = fm * 16 + (lane & 15);
    int k0 = kc * 64 + (lane >> 4) * 16;
    const float* p = st + (size_t)row * DIM + k0;
    signed char h[16], l[16];
#pragma unroll
    for (int b = 0; b < 16; b++) {
        int q = (int)rintf(p[b] * 16384.f);
        q = q > 16383 ? 16383 : (q < -16383 ? -16383 : q);
        h[b] = (signed char)(q >> 7);
        l[b] = (signed char)(q & 127);
    }
    *(i32x4*)(Sh + (size_t)t * 16) = *(const i32x4*)h;
    *(i32x4*)(Sl + (size_t)t * 16) = *(const i32x4*)l;
}

// drive (row-major f32) -> epilogue-order packed: float4 index
// ((tile*2+i)*4+j)*64+lane holds g=0..3 with row=tm*32+i*16+quad*4+g,
// col=tn*64+j*16+l16, tile=tm*32+tn.
__global__ __launch_bounds__(256) void repack_drive(
    const float* __restrict__ drive, float* __restrict__ dp) {
    int t = blockIdx.x * 256 + threadIdx.x;           // 1048576 threads
    int lane = t & 63, j = (t >> 6) & 3, iw = (t >> 8) & 1, tile = t >> 9;
    int tm = tile >> 5, tn = tile & 31;
    int quad = lane >> 4, l16 = lane & 15;
    int col = tn * 64 + j * 16 + l16;
    f32x4 v;
#pragma unroll
    for (int g = 0; g < 4; g++)
        v[g] = drive[(size_t)(tm * 32 + iw * 16 + quad * 4 + g) * DIM + col];
    ((f32x4*)dp)[t] = v;
}

// ---------------- bf16 dual-A GEMM (drive), tile 64x128, dbuf (R3) ----------------
template <int MODE>
__global__ __launch_bounds__(256) void gemm_bf16(
    const unsigned short* __restrict__ Ahi,
    const unsigned short* __restrict__ Alo,
    const unsigned short* __restrict__ BT,
    const float* __restrict__ Cin,
    const float* __restrict__ bias,
    float* __restrict__ Cout) {
    __shared__ alignas(16) char sA[2][16384];
    __shared__ alignas(16) char sB[2][16384];

    const int bid = blockIdx.x;
    const int xcd = bid & 7, slot = bid >> 3;
    const int tm = ((xcd >> 1) << 3) + (slot >> 3);
    const int tn = ((xcd & 1) << 3) + (slot & 7);
    const int row0 = tm << 6, col0 = tn << 7;

    const int tid = threadIdx.x;
    const int lane = tid & 63;
    const int quad = lane >> 4, l16 = lane & 15;
    const int wave = tid >> 6;
    const int wm = wave >> 1, wn = wave & 1;

    const unsigned short* a_src[4]; int a_dst[4];
    const unsigned short* b_src[4]; int b_dst[4];
#pragma unroll
    for (int i = 0; i < 4; i++) {
        int s = tid + 256 * i;
        {
            int r = s >> 4, g = (s >> 3) & 1, c = (s & 7) ^ (r & 7);
            a_src[i] = (g ? Alo : Ahi) + (size_t)(row0 + r) * DIM + c * 8;
            a_dst[i] = s * 16;
        }
        {
            int r = s >> 3, c = (s & 7) ^ (r & 7);
            b_src[i] = BT + (size_t)(col0 + r) * DIM + c * 8;
            b_dst[i] = s * 16;
        }
    }

    f32x4 acc[2][4] = {};

    auto stage = [&](int p, int k0) {
#pragma unroll
        for (int i = 0; i < 4; i++) {
            async16(a_src[i] + k0, sA[p] + a_dst[i]);
            async16(b_src[i] + k0, sB[p] + b_dst[i]);
        }
    };

    stage(0, 0);
    __syncthreads();
    for (int it = 0; it < 32; it++) {
        const int p = it & 1;
        if (it + 1 < 32) stage(1 - p, (it + 1) * 64);
#pragma unroll
        for (int kk = 0; kk < 2; kk++) {
            bf16x8 ah[2], al[2], bv[4];
#pragma unroll
            for (int i = 0; i < 2; i++) {
                const int r = (wm << 5) + (i << 4) + l16;
                const int cs = ((kk << 2) + quad) ^ (r & 7);
                ah[i] = ld_bf16_frag(sA[p] + ((r << 4) + cs) * 16);
                al[i] = ld_bf16_frag(sA[p] + ((r << 4) + 8 + cs) * 16);
            }
#pragma unroll
            for (int j = 0; j < 4; j++) {
                const int r = (wn << 6) + (j << 4) + l16;
                const int cs = ((kk << 2) + quad) ^ (r & 7);
                bv[j] = ld_bf16_frag(sB[p] + ((r << 3) + cs) * 16);
            }
#pragma unroll
            for (int i = 0; i < 2; i++)
#pragma unroll
                for (int j = 0; j < 4; j++) {
                    acc[i][j] = __builtin_amdgcn_mfma_f32_16x16x32_bf16(ah[i], bv[j], acc[i][j], 0, 0, 0);
                    acc[i][j] = __builtin_amdgcn_mfma_f32_16x16x32_bf16(al[i], bv[j], acc[i][j], 0, 0, 0);
                }
        }
        __syncthreads();
    }

#pragma unroll
    for (int i = 0; i < 2; i++) {
        const int rb = row0 + (wm << 5) + (i << 4) + (quad << 2);
#pragma unroll
        for (int j = 0; j < 4; j++) {
            const int c = col0 + (wn << 6) + (j << 4) + l16;
#pragma unroll
            for (int g = 0; g < 4; g++) {
                const size_t idx = (size_t)(rb + g) * DIM + c;
                if (MODE == 0) Cout[idx] = acc[i][j][g];
                else           Cout[idx] = Cin[idx] + acc[i][j][g] + bias[c];
            }
        }
    }
}

// ---------------- i8 step: packed streaming + 2-way split-K ----------------
// Block = 128 thr (2 waves). Both waves compute the full 32(m)x64(n) tile,
// each over half of K (fragment-packed operands: every load = contiguous 1KB
// = 8 full cache lines). LDS cross-wave reduction; wave w finishes i=w half
// of the epilogue and writes next state fragment-packed.
__global__ __launch_bounds__(128) void step_i8p(
    const signed char* __restrict__ Sh,   // packed state hi (4MB)
    const signed char* __restrict__ Sl,   // packed state lo
    const signed char* __restrict__ Bp,   // packed adjacency
    const float* __restrict__ dp,         // packed drive
    float* __restrict__ out,
    signed char* __restrict__ Oh,         // next state (packed)
    signed char* __restrict__ Ol,
    int write_f32) {
    __shared__ i32x4 red[2][8][64];       // [wave][j*2+hl][lane] = 16KB

    const int bid = blockIdx.x;
    const int xcd = bid & 7, slot = bid >> 3;       // m-stripe per XCD (R5 fix)
    const int tm = (xcd << 3) + (slot >> 5);        // 0..63
    const int tn = slot & 31;                        // 0..31

    const int tid = threadIdx.x;
    const int lane = tid & 63;
    const int w = tid >> 6;                          // split-K wave 0/1
    const int quad = lane >> 4, l16 = lane & 15;

    // packed block (f,kc) lives at byte (f*32 + kc)*1024; this wave's K-half
    // starts at kc = w*16.
    const size_t half = (size_t)w * 16384;
    const signed char* a0h = Sh + (size_t)(tm * 2) * 32768 + half + lane * 16;
    const signed char* a1h = a0h + 32768;
    const signed char* a0l = Sl + (size_t)(tm * 2) * 32768 + half + lane * 16;
    const signed char* a1l = a0l + 32768;
    const signed char* b0 = Bp + (size_t)(tn * 4) * 32768 + half + lane * 16;
    const signed char* b1 = b0 + 32768;
    const signed char* b2 = b0 + 65536;
    const signed char* b3 = b0 + 98304;

    i32x4 acch[2][4] = {};
    i32x4 accl[2][4] = {};
    i32x4 A0[4], B0[4], A1[4], B1[4];

    A0[0] = *(const i32x4*)(a0h); A0[1] = *(const i32x4*)(a1h);
    A0[2] = *(const i32x4*)(a0l); A0[3] = *(const i32x4*)(a1l);
    B0[0] = *(const i32x4*)(b0);  B0[1] = *(const i32x4*)(b1);
    B0[2] = *(const i32x4*)(b2);  B0[3] = *(const i32x4*)(b3);

#define MFMA16(F)                                                                    \
    do {                                                                             \
        acch[0][0] = __builtin_amdgcn_mfma_i32_16x16x64_i8(F[0], F##B[0], acch[0][0], 0, 0, 0); \
        acch[0][1] = __builtin_amdgcn_mfma_i32_16x16x64_i8(F[0], F##B[1], acch[0][1], 0, 0, 0); \
        acch[0][2] = __builtin_amdgcn_mfma_i32_16x16x64_i8(F[0], F##B[2], acch[0][2], 0, 0, 0); \
        acch[0][3] = __builtin_amdgcn_mfma_i32_16x16x64_i8(F[0], F##B[3], acch[0][3], 0, 0, 0); \
        acch[1][0] = __builtin_amdgcn_mfma_i32_16x16x64_i8(F[1], F##B[0], acch[1][0], 0, 0, 0); \
        acch[1][1] = __builtin_amdgcn_mfma_i32_16x16x64_i8(F[1], F##B[1], acch[1][1], 0, 0, 0); \
        acch[1][2] = __builtin_amdgcn_mfma_i32_16x16x64_i8(F[1], F##B[2], acch[1][2], 0, 0, 0); \
        acch[1][3] = __builtin_amdgcn_mfma_i32_16x16x64_i8(F[1], F##B[3], acch[1][3], 0, 0, 0); \
        accl[0][0] = __builtin_amdgcn_mfma_i32_16x16x64_i8(F[2], F##B[0], accl[0][0], 0, 0, 0); \
        accl[0][1] = __builtin_amdgcn_mfma_i32_16x16x64_i8(F[2], F##B[1], accl[0][1], 0, 0, 0); \
        accl[0][2] = __builtin_amdgcn_mfma_i32_16x16x64_i8(F[2], F##B[2], accl[0][2], 0, 0, 0); \
        accl[0][3] = __builtin_amdgcn_mfma_i32_16x16x64_i8(F[2], F##B[3], accl[0][3], 0, 0, 0); \
        accl[1][0] = __builtin_amdgcn_mfma_i32_16x16x64_i8(F[3], F##B[0], accl[1][0], 0, 0, 0); \
        accl[1][1] = __builtin_amdgcn_mfma_i32_16x16x64_i8(F[3], F##B[1], accl[1][1], 0, 0, 0); \
        accl[1][2] = __builtin_amdgcn_mfma_i32_16x16x64_i8(F[3], F##B[2], accl[1][2], 0, 0, 0); \
        accl[1][3] = __builtin_amdgcn_mfma_i32_16x16x64_i8(F[3], F##B[3], accl[1][3], 0, 0, 0); \
    } while (0)
#define A0B B0
#define A1B B1

#pragma unroll 1
    for (int k0 = 0; k0 < 16384; k0 += 2048) {       // 16 packed kc blocks
        A1[0] = *(const i32x4*)(a0h + k0 + 1024); A1[1] = *(const i32x4*)(a1h + k0 + 1024);
        A1[2] = *(const i32x4*)(a0l + k0 + 1024); A1[3] = *(const i32x4*)(a1l + k0 + 1024);
        B1[0] = *(const i32x4*)(b0 + k0 + 1024);  B1[1] = *(const i32x4*)(b1 + k0 + 1024);
        B1[2] = *(const i32x4*)(b2 + k0 + 1024);  B1[3] = *(const i32x4*)(b3 + k0 + 1024);
        MFMA16(A0);
        if (k0 + 2048 < 16384) {
            A0[0] = *(const i32x4*)(a0h + k0 + 2048); A0[1] = *(const i32x4*)(a1h + k0 + 2048);
            A0[2] = *(const i32x4*)(a0l + k0 + 2048); A0[3] = *(const i32x4*)(a1l + k0 + 2048);
            B0[0] = *(const i32x4*)(b0 + k0 + 2048);  B0[1] = *(const i32x4*)(b1 + k0 + 2048);
            B0[2] = *(const i32x4*)(b2 + k0 + 2048);  B0[3] = *(const i32x4*)(b3 + k0 + 2048);
        }
        MFMA16(A1);
    }
#undef MFMA16
#undef A0B
#undef A1B

    // split-K reduction: wave w ships its partial for i=1-w, keeps i=w.
#pragma unroll
    for (int j = 0; j < 4; j++) {
        red[w][j * 2 + 0][lane] = acch[1 - w][j];
        red[w][j * 2 + 1][lane] = accl[1 - w][j];
    }
    __syncthreads();
#pragma unroll
    for (int j = 0; j < 4; j++) {
        i32x4 oh = red[1 - w][j * 2 + 0][lane];
        i32x4 ol = red[1 - w][j * 2 + 1][lane];
#pragma unroll
        for (int g = 0; g < 4; g++) { acch[w][j][g] += oh[g]; accl[w][j][g] += ol[g]; }
    }

    // epilogue (wave w owns i=w): rows tm*32+w*16+quad*4+g, cols tn*64+j*16+l16.
    const int tile = (tm << 5) + tn;
    const size_t sbase = (size_t)(tm * 2 + w) * 32768 + (size_t)tn * 1024;
    const f32x4* dpp = (const f32x4*)dp + ((size_t)(tile * 2 + w) * 4) * 64 + lane;
#pragma unroll
    for (int j = 0; j < 4; j++) {
        f32x4 dv = dpp[j * 64];
#pragma unroll
        for (int g = 0; g < 4; g++) {
            const size_t inner = sbase + (size_t)((j * 16 + quad * 4 + g) * 16 + l16);
            int prod = acch[w][j][g] * 128 + accl[w][j][g];   // exact int
            float y = dv[g] + (float)prod * (1.0f / 16384.0f);
            float sold = (float)((int)Sh[inner] * 128 + (int)Sl[inner]) * (1.0f / 16384.0f);
            float e = __expf(2.0f * y);
            float th = 1.0f - 2.0f / (e + 1.0f);
            float s = (1.0f - LEAK) * sold + LEAK * th;
            if (write_f32)
                out[(size_t)(tm * 32 + w * 16 + quad * 4 + g) * DIM + tn * 64 + j * 16 + l16] = s;
            int q = (int)rintf(s * 16384.f);
            q = q > 16383 ? 16383 : (q < -16383 ? -16383 : q);
            Oh[inner] = (signed char)(q >> 7);
            Ol[inner] = (signed char)(q & 127);
        }
    }
}

extern "C" void kernel_launch(void* const* d_in, const int* in_sizes, int n_in,
                              void* d_out, int out_size, void* d_ws, size_t ws_size,
                              hipStream_t stream) {
    const float* x    = (const float*)d_in[0];
    const float* wgt  = (const float*)d_in[1];
    const float* adj  = (const float*)d_in[2];
    const float* bias = (const float*)d_in[3];
    const float* st0  = (const float*)d_in[4];
    float* out = (float*)d_out;

    const size_t NE = (size_t)DIM * DIM;
    // ws (56 MB): adjT(4) | Bp(4) | drive(16) | bufA(8) bufB(8) bufC(8) bufD(8)
    // After the drive GEMMs retire (stream-ordered): drive_p aliases bufA+bufB,
    // packed state ping-pong aliases bufC (S1h,S1l) and bufD (S2h,S2l).
    signed char* adjT = (signed char*)d_ws;
    signed char* Bp   = adjT + NE;
    float* drive = (float*)(Bp + NE);
    unsigned short* bufA = (unsigned short*)(drive + NE);
    unsigned short* bufB = bufA + NE;
    unsigned short* bufC = bufB + NE;
    unsigned short* bufD = bufC + NE;
    float* drive_p = (float*)bufA;                    // 16MB
    signed char* S1h = (signed char*)bufC;            // 4MB
    signed char* S1l = S1h + NE;
    signed char* S2h = (signed char*)bufD;
    signed char* S2l = S2h + NE;

    dim3 blk(256);
    transpose_split<<<dim3(64, 64), blk, 0, stream>>>(wgt, bufC, bufD);
    split_kernel<<<dim3(4096), blk, 0, stream>>>(x, bufA, bufB);
    transpose_i8<<<dim3(64, 64), blk, 0, stream>>>(adj, adjT);
    pack_b<<<dim3(1024), blk, 0, stream>>>(adjT, Bp);

    gemm_bf16<0><<<dim3(512), blk, 0, stream>>>(bufA, bufB, bufC, (const float*)0,
                                                (const float*)0, drive);
    gemm_bf16<1><<<dim3(512), blk, 0, stream>>>(bufA, bufB, bufD, drive, bias, drive);

    // after drive is final: repack it and the initial state (aliases safe in
    // stream order: bufA/bufB/bufC/bufD no longer read by later GEMMs)
    repack_drive<<<dim3(4096), blk, 0, stream>>>(drive, drive_p);
    quant_pack<<<dim3(1024), blk, 0, stream>>>(st0, S1h, S1l);

    signed char* hi = S1h; signed char* li = S1l;
    signed char* ho = S2h; signed char* lo = S2l;
    for (int t = 0; t < 64; t++) {
        step_i8p<<<dim3(2048), dim3(128), 0, stream>>>(hi, li, Bp, drive_p, out,
                                                       ho, lo, (t == 63) ? 1 : 0);
        signed char* th = hi; hi = ho; ho = th;
        signed char* tl = li; li = lo; lo = tl;
    }
}

// Round 7
// 2700.730 us; speedup vs baseline: 1.9001x; 1.9001x over previous
//
#include <hip/hip_runtime.h>

#define DIM 2048
#define LEAK 0.2f

typedef __bf16 bf16x8 __attribute__((ext_vector_type(8)));
typedef float  f32x4  __attribute__((ext_vector_type(4)));
typedef unsigned int u32x4 __attribute__((ext_vector_type(4)));
typedef int    i32x4  __attribute__((ext_vector_type(4)));

static __device__ __forceinline__ unsigned short f2bf(float f) {
    unsigned int x = __float_as_uint(f);
    return (unsigned short)((x + 0x7fffu + ((x >> 16) & 1u)) >> 16);  // RNE
}
static __device__ __forceinline__ float bf2f(unsigned short h) {
    return __uint_as_float(((unsigned int)h) << 16);
}

static __device__ __forceinline__ void async16(const void* g, void* s) {
    __builtin_amdgcn_global_load_lds(
        (const __attribute__((address_space(1))) void*)g,
        (__attribute__((address_space(3))) void*)s, 16, 0, 0);
}

static __device__ __forceinline__ bf16x8 ld_bf16_frag(const char* p) {
    union { u32x4 u; bf16x8 v; } cv;
    cv.u = *(const u32x4*)p;   // ds_read_b128
    return cv.v;
}

// ---------------- prep kernels ----------------

__global__ __launch_bounds__(256) void split_kernel(
    const float* __restrict__ in,
    unsigned short* __restrict__ hi, unsigned short* __restrict__ lo) {
    int idx = blockIdx.x * 256 + threadIdx.x;
    float4 v = ((const float4*)in)[idx];
    ushort4 h, l;
    h.x = f2bf(v.x); l.x = f2bf(v.x - bf2f(h.x));
    h.y = f2bf(v.y); l.y = f2bf(v.y - bf2f(h.y));
    h.z = f2bf(v.z); l.z = f2bf(v.z - bf2f(h.z));
    h.w = f2bf(v.w); l.w = f2bf(v.w - bf2f(h.w));
    ((ushort4*)hi)[idx] = h;
    ((ushort4*)lo)[idx] = l;
}

__global__ __launch_bounds__(256) void transpose_split(
    const float* __restrict__ in,
    unsigned short* __restrict__ hiT, unsigned short* __restrict__ loT) {
    __shared__ float t[32][33];
    int bx = blockIdx.x, by = blockIdx.y;
    int tx = threadIdx.x & 31, ty4 = (threadIdx.x >> 5) << 2;
#pragma unroll
    for (int i = 0; i < 4; i++)
        t[ty4 + i][tx] = in[(size_t)(by * 32 + ty4 + i) * DIM + bx * 32 + tx];
    __syncthreads();
#pragma unroll
    for (int i = 0; i < 4; i++) {
        float v = t[tx][ty4 + i];
        size_t o = (size_t)(bx * 32 + ty4 + i) * DIM + by * 32 + tx;
        unsigned short h = f2bf(v);
        hiT[o] = h;
        loT[o] = f2bf(v - bf2f(h));
    }
}

__global__ __launch_bounds__(256) void transpose_i8(
    const float* __restrict__ in, signed char* __restrict__ outT) {
    __shared__ float t[32][33];
    int bx = blockIdx.x, by = blockIdx.y;
    int tx = threadIdx.x & 31, ty4 = (threadIdx.x >> 5) << 2;
#pragma unroll
    for (int i = 0; i < 4; i++)
        t[ty4 + i][tx] = in[(size_t)(by * 32 + ty4 + i) * DIM + bx * 32 + tx];
    __syncthreads();
#pragma unroll
    for (int i = 0; i < 4; i++)
        outT[(size_t)(bx * 32 + ty4 + i) * DIM + by * 32 + tx] =
            (signed char)t[tx][ty4 + i];
}

// adjT[n][k] -> fragment-packed Bp: block (nf,kc) is 1KB at (nf*32+kc)*1024;
// lane L holds col = nf*16 + (L&15), k bytes [kc*64 + (L>>4)*16, +16).
__global__ __launch_bounds__(256) void pack_b(
    const signed char* __restrict__ adjT, signed char* __restrict__ Bp) {
    int t = blockIdx.x * 256 + threadIdx.x;           // 262144 threads
    int lane = t & 63, kc = (t >> 6) & 31, nf = t >> 11;
    int col = nf * 16 + (lane & 15);
    int k0 = kc * 64 + (lane >> 4) * 16;
    i32x4 v = *(const i32x4*)(adjT + (size_t)col * DIM + k0);
    *(i32x4*)(Bp + (size_t)t * 16) = v;
}

// fp32 state -> packed int15 split: h = q>>7 (i8), ln = -(q&127) (i8, [-127,0]).
// Same block layout as pack_b (rows instead of cols).
__global__ __launch_bounds__(256) void quant_pack_n(
    const float* __restrict__ st,
    signed char* __restrict__ Sh, signed char* __restrict__ Sln) {
    int t = blockIdx.x * 256 + threadIdx.x;           // 262144 threads
    int lane = t & 63, kc = (t >> 6) & 31, fm = t >> 11;
    int row = fm * 16 + (lane & 15);
    int k0 = kc * 64 + (lane >> 4) * 16;
    const float* p = st + (size_t)row * DIM + k0;
    signed char h[16], l[16];
#pragma unroll
    for (int b = 0; b < 16; b++) {
        int q = (int)rintf(p[b] * 16384.f);
        q = q > 16383 ? 16383 : (q < -16383 ? -16383 : q);
        h[b] = (signed char)(q >> 7);
        l[b] = (signed char)(-(q & 127));
    }
    *(i32x4*)(Sh + (size_t)t * 16) = *(const i32x4*)h;
    *(i32x4*)(Sln + (size_t)t * 16) = *(const i32x4*)l;
}

// ---------------- bf16 dual-A GEMM (drive), tile 64x128, dbuf (R3) ----------------
template <int MODE>
__global__ __launch_bounds__(256) void gemm_bf16(
    const unsigned short* __restrict__ Ahi,
    const unsigned short* __restrict__ Alo,
    const unsigned short* __restrict__ BT,
    const float* __restrict__ Cin,
    const float* __restrict__ bias,
    float* __restrict__ Cout) {
    __shared__ alignas(16) char sA[2][16384];
    __shared__ alignas(16) char sB[2][16384];

    const int bid = blockIdx.x;
    const int xcd = bid & 7, slot = bid >> 3;
    const int tm = ((xcd >> 1) << 3) + (slot >> 3);
    const int tn = ((xcd & 1) << 3) + (slot & 7);
    const int row0 = tm << 6, col0 = tn << 7;

    const int tid = threadIdx.x;
    const int lane = tid & 63;
    const int quad = lane >> 4, l16 = lane & 15;
    const int wave = tid >> 6;
    const int wm = wave >> 1, wn = wave & 1;

    const unsigned short* a_src[4]; int a_dst[4];
    const unsigned short* b_src[4]; int b_dst[4];
#pragma unroll
    for (int i = 0; i < 4; i++) {
        int s = tid + 256 * i;
        {
            int r = s >> 4, g = (s >> 3) & 1, c = (s & 7) ^ (r & 7);
            a_src[i] = (g ? Alo : Ahi) + (size_t)(row0 + r) * DIM + c * 8;
            a_dst[i] = s * 16;
        }
        {
            int r = s >> 3, c = (s & 7) ^ (r & 7);
            b_src[i] = BT + (size_t)(col0 + r) * DIM + c * 8;
            b_dst[i] = s * 16;
        }
    }

    f32x4 acc[2][4] = {};

    auto stage = [&](int p, int k0) {
#pragma unroll
        for (int i = 0; i < 4; i++) {
            async16(a_src[i] + k0, sA[p] + a_dst[i]);
            async16(b_src[i] + k0, sB[p] + b_dst[i]);
        }
    };

    stage(0, 0);
    __syncthreads();
    for (int it = 0; it < 32; it++) {
        const int p = it & 1;
        if (it + 1 < 32) stage(1 - p, (it + 1) * 64);
#pragma unroll
        for (int kk = 0; kk < 2; kk++) {
            bf16x8 ah[2], al[2], bv[4];
#pragma unroll
            for (int i = 0; i < 2; i++) {
                const int r = (wm << 5) + (i << 4) + l16;
                const int cs = ((kk << 2) + quad) ^ (r & 7);
                ah[i] = ld_bf16_frag(sA[p] + ((r << 4) + cs) * 16);
                al[i] = ld_bf16_frag(sA[p] + ((r << 4) + 8 + cs) * 16);
            }
#pragma unroll
            for (int j = 0; j < 4; j++) {
                const int r = (wn << 6) + (j << 4) + l16;
                const int cs = ((kk << 2) + quad) ^ (r & 7);
                bv[j] = ld_bf16_frag(sB[p] + ((r << 3) + cs) * 16);
            }
#pragma unroll
            for (int i = 0; i < 2; i++)
#pragma unroll
                for (int j = 0; j < 4; j++) {
                    acc[i][j] = __builtin_amdgcn_mfma_f32_16x16x32_bf16(ah[i], bv[j], acc[i][j], 0, 0, 0);
                    acc[i][j] = __builtin_amdgcn_mfma_f32_16x16x32_bf16(al[i], bv[j], acc[i][j], 0, 0, 0);
                }
        }
        __syncthreads();
    }

#pragma unroll
    for (int i = 0; i < 2; i++) {
        const int rb = row0 + (wm << 5) + (i << 4) + (quad << 2);
#pragma unroll
        for (int j = 0; j < 4; j++) {
            const int c = col0 + (wn << 6) + (j << 4) + l16;
#pragma unroll
            for (int g = 0; g < 4; g++) {
                const size_t idx = (size_t)(rb + g) * DIM + c;
                if (MODE == 0) Cout[idx] = acc[i][j][g];
                else           Cout[idx] = Cin[idx] + acc[i][j][g] + bias[c];
            }
        }
    }
}

// ---------------- i8 step v7: A-direct + B-LDS, single accumulator ----------------
// Tile 64(m) x 128(n), 4 waves (2x2), wave-tile 32x64, BK = 64 k-bytes.
// acc accumulates -q.B exactly: mfma(h, B<<7) + mfma(-l, B)
//   (B bytes are 0/1, so B<<7 per dword = bytes 0x80 = -128, no carry).
// A (packed state) loaded straight from global, register-dbuffed; B staged
// via LDS dbuf (dedup: B set per XCD = 4MB = one L2). All register-array
// indices are compile-time (R6's runtime-'w' scratch bug excluded).
__global__ __launch_bounds__(256, 3) void step_v7(
    const signed char* __restrict__ Sh,    // packed hi
    const signed char* __restrict__ Sln,   // packed -(lo)
    const signed char* __restrict__ Bp,    // packed adjacency 0/1
    const float* __restrict__ drive,       // row-major fp32
    float* __restrict__ out,
    signed char* __restrict__ Oh,
    signed char* __restrict__ Oln,
    int write_f32) {
    __shared__ alignas(16) signed char sB[2][8192];

    const int bid = blockIdx.x;
    const int xcd = bid & 7, slot = bid >> 3;       // m-stripe: XCD owns 4 m-tiles x 16 n
    const int tm = (xcd << 2) + (slot >> 4);        // 0..31
    const int tn = slot & 15;                        // 0..15

    const int tid = threadIdx.x;
    const int lane = tid & 63, wave = tid >> 6;
    const int quad = lane >> 4, l16 = lane & 15;
    const int wm = wave >> 1, wn = wave & 1;

    // B staging: tile = 8 nf-blocks x 1KB; chunk s = tid + 256*i.
    // Within a wave s>>6 is uniform -> LDS dst = uniform base + lane*16 (legal).
    const signed char* b_src[2]; int b_dst[2];
#pragma unroll
    for (int i = 0; i < 2; i++) {
        int s = tid + 256 * i;
        b_src[i] = Bp + ((size_t)(tn * 8 + (s >> 6)) * 32) * 1024 + (s & 63) * 16;
        b_dst[i] = s * 16;
    }

    // A pointers: wave's 2 fm blocks (fm = tm*4 + wm*2 + {0,1})
    const signed char* a_h0 = Sh  + ((size_t)(tm * 4 + wm * 2) * 32) * 1024 + lane * 16;
    const signed char* a_h1 = a_h0 + 32768;
    const signed char* a_l0 = Sln + ((size_t)(tm * 4 + wm * 2) * 32) * 1024 + lane * 16;
    const signed char* a_l1 = a_l0 + 32768;

    i32x4 acc[2][4] = {};
    i32x4 A0[4], A1[4];

#define COMPUTE(P, AB)                                                               \
    do {                                                                             \
        _Pragma("unroll")                                                            \
        for (int j = 0; j < 4; j++) {                                                \
            i32x4 b = *(const i32x4*)(sB[P] + ((wn * 4 + j) * 64 + lane) * 16);      \
            i32x4 bs = (i32x4)(((u32x4)b) << 7);                                     \
            acc[0][j] = __builtin_amdgcn_mfma_i32_16x16x64_i8(AB[0], bs, acc[0][j], 0, 0, 0); \
            acc[1][j] = __builtin_amdgcn_mfma_i32_16x16x64_i8(AB[1], bs, acc[1][j], 0, 0, 0); \
            acc[0][j] = __builtin_amdgcn_mfma_i32_16x16x64_i8(AB[2], b,  acc[0][j], 0, 0, 0); \
            acc[1][j] = __builtin_amdgcn_mfma_i32_16x16x64_i8(AB[3], b,  acc[1][j], 0, 0, 0); \
        }                                                                            \
    } while (0)

    // prologue: kc=0
    async16(b_src[0], sB[0] + b_dst[0]);
    async16(b_src[1], sB[0] + b_dst[1]);
    A0[0] = *(const i32x4*)(a_h0); A0[1] = *(const i32x4*)(a_h1);
    A0[2] = *(const i32x4*)(a_l0); A0[3] = *(const i32x4*)(a_l1);
    __syncthreads();

#pragma unroll 1
    for (int kc = 0; kc < 32; kc += 2) {
        // half A: consume sB[0] + A0 (kc); prefetch kc+1
        {
            const int kn = (kc + 1) * 1024;
            async16(b_src[0] + kn, sB[1] + b_dst[0]);
            async16(b_src[1] + kn, sB[1] + b_dst[1]);
            A1[0] = *(const i32x4*)(a_h0 + kn); A1[1] = *(const i32x4*)(a_h1 + kn);
            A1[2] = *(const i32x4*)(a_l0 + kn); A1[3] = *(const i32x4*)(a_l1 + kn);
        }
        COMPUTE(0, A0);
        __syncthreads();
        // half B: consume sB[1] + A1 (kc+1); prefetch kc+2
        if (kc + 2 < 32) {
            const int kn = (kc + 2) * 1024;
            async16(b_src[0] + kn, sB[0] + b_dst[0]);
            async16(b_src[1] + kn, sB[0] + b_dst[1]);
            A0[0] = *(const i32x4*)(a_h0 + kn); A0[1] = *(const i32x4*)(a_h1 + kn);
            A0[2] = *(const i32x4*)(a_l0 + kn); A0[3] = *(const i32x4*)(a_l1 + kn);
        }
        COMPUTE(1, A1);
        __syncthreads();
    }
#undef COMPUTE

    // epilogue: C/D layout col = lane&15, row = quad*4 + g (verified).
    // acc = -q.B  ->  prod = -acc = 16384*(s@A).
#pragma unroll
    for (int i = 0; i < 2; i++) {
        const int rb = tm * 64 + wm * 32 + i * 16 + (quad << 2);
        const int fm = tm * 4 + wm * 2 + i;
        const int kc_out = tn * 2 + wn;
        const size_t sbase = ((size_t)fm * 32 + kc_out) * 1024;
#pragma unroll
        for (int j = 0; j < 4; j++) {
            const int c = tn * 128 + wn * 64 + j * 16 + l16;
#pragma unroll
            for (int g = 0; g < 4; g++) {
                const int r = rb + g;
                const size_t idx = (size_t)r * DIM + c;
                const size_t inner = sbase + (size_t)((j * 16 + (quad << 2) + g) * 16 + l16);
                int prod = -acc[i][j][g];                      // exact int
                float y = drive[idx] + (float)prod * (1.0f / 16384.0f);
                int soldq = ((int)Sh[inner] << 7) - (int)Sln[inner];
                float sold = (float)soldq * (1.0f / 16384.0f);
                float e = __expf(2.0f * y);
                float th = 1.0f - 2.0f / (e + 1.0f);
                float s = (1.0f - LEAK) * sold + LEAK * th;
                if (write_f32) out[idx] = s;
                int q = (int)rintf(s * 16384.f);
                q = q > 16383 ? 16383 : (q < -16383 ? -16383 : q);
                Oh[inner]  = (signed char)(q >> 7);
                Oln[inner] = (signed char)(-(q & 127));
            }
        }
    }
}

extern "C" void kernel_launch(void* const* d_in, const int* in_sizes, int n_in,
                              void* d_out, int out_size, void* d_ws, size_t ws_size,
                              hipStream_t stream) {
    const float* x    = (const float*)d_in[0];
    const float* wgt  = (const float*)d_in[1];
    const float* adj  = (const float*)d_in[2];
    const float* bias = (const float*)d_in[3];
    const float* st0  = (const float*)d_in[4];
    float* out = (float*)d_out;

    const size_t NE = (size_t)DIM * DIM;
    // ws (56 MB): adjT(4) | Bp(4) | drive(16) | bufA(8) bufB(8) bufC(8) bufD(8)
    // Packed state ping-pong aliases bufC/bufD after the drive GEMMs retire.
    signed char* adjT = (signed char*)d_ws;
    signed char* Bp   = adjT + NE;
    float* drive = (float*)(Bp + NE);
    unsigned short* bufA = (unsigned short*)(drive + NE);
    unsigned short* bufB = bufA + NE;
    unsigned short* bufC = bufB + NE;
    unsigned short* bufD = bufC + NE;
    signed char* S1h = (signed char*)bufC;
    signed char* S1l = S1h + NE;
    signed char* S2h = (signed char*)bufD;
    signed char* S2l = S2h + NE;

    dim3 blk(256);
    transpose_split<<<dim3(64, 64), blk, 0, stream>>>(wgt, bufC, bufD);
    split_kernel<<<dim3(4096), blk, 0, stream>>>(x, bufA, bufB);
    transpose_i8<<<dim3(64, 64), blk, 0, stream>>>(adj, adjT);
    pack_b<<<dim3(1024), blk, 0, stream>>>(adjT, Bp);

    gemm_bf16<0><<<dim3(512), blk, 0, stream>>>(bufA, bufB, bufC, (const float*)0,
                                                (const float*)0, drive);
    gemm_bf16<1><<<dim3(512), blk, 0, stream>>>(bufA, bufB, bufD, drive, bias, drive);

    // initial state -> packed split (aliases bufC region; GEMMs are done in
    // stream order)
    quant_pack_n<<<dim3(1024), blk, 0, stream>>>(st0, S1h, S1l);

    signed char* hi = S1h; signed char* li = S1l;
    signed char* ho = S2h; signed char* lo = S2l;
    for (int t = 0; t < 64; t++) {
        step_v7<<<dim3(512), blk, 0, stream>>>(hi, li, Bp, drive, out,
                                               ho, lo, (t == 63) ? 1 : 0);
        signed char* th = hi; hi = ho; ho = th;
        signed char* tl = li; li = lo; lo = tl;
    }
}